// Round 4
// baseline (396.813 us; speedup 1.0000x reference)
//
#include <hip/hip_runtime.h>
#include <hip/hip_bf16.h>

typedef __attribute__((ext_vector_type(8))) short bf16x8;
typedef __attribute__((ext_vector_type(4))) float f32x4;
typedef unsigned short ushort_t;

__device__ __forceinline__ void gload16(const void* g, void* l) {
  __builtin_amdgcn_global_load_lds(
      (const __attribute__((address_space(1))) void*)g,
      (__attribute__((address_space(3))) void*)l, 16, 0, 0);
}

// ---------------- K1: styles[n][ci] = w[n] . affine_w[ci] * (1/sqrt(512)) + affine_b[ci]
__global__ void k_styles(const float* __restrict__ w, const float* __restrict__ aw,
                         const float* __restrict__ ab, float* __restrict__ styles) {
  int wave = threadIdx.x >> 6, l = threadIdx.x & 63;
  int id = blockIdx.x * 4 + wave;   // 0..2047
  int n = id >> 8, ci = id & 255;
  const float4* ar = (const float4*)(aw + (size_t)ci * 512);
  const float4* wr = (const float4*)(w + n * 512);
  float s = 0.f;
  #pragma unroll
  for (int j = 0; j < 2; j++) {
    float4 a = ar[l * 2 + j], b = wr[l * 2 + j];
    s += a.x * b.x + a.y * b.y + a.z * b.z + a.w * b.w;
  }
  #pragma unroll
  for (int off = 32; off; off >>= 1) s += __shfl_xor(s, off, 64);
  if (l == 0) styles[n * 256 + ci] = s * 0.044194173824159216f + ab[ci];
}

// ---------------- K2: modulate + demodulate, write bf16 weights
// layout: wwg[n][kh][cc=ci/32][kw][co 256][ci%32]   (ci-contiguous 64B rows)
__global__ __launch_bounds__(256) void k_modw(const float* __restrict__ weight,
                                              const float* __restrict__ styles,
                                              ushort_t* __restrict__ wwg) {
  __shared__ float wl[4][2304];
  __shared__ float s_sty[256];
  int wave = threadIdx.x >> 6, l = threadIdx.x & 63;
  int id = blockIdx.x * 4 + wave;  // (n, co); n uniform within block
  int n = id >> 8, co = id & 255;
  s_sty[threadIdx.x] = styles[(size_t)n * 256 + threadIdx.x];
  __syncthreads();
  const float* wrow = weight + (size_t)co * 2304;   // flat [ci][kh][kw]
  float sq = 0.f;
  #pragma unroll
  for (int i = 0; i < 36; i++) {
    int idx = i * 64 + l;
    float v = wrow[idx] * s_sty[idx / 9];
    sq += v * v;
    wl[wave][idx] = v;
  }
  #pragma unroll
  for (int off = 32; off; off >>= 1) sq += __shfl_xor(sq, off, 64);
  float d = rsqrtf(sq + 1e-8f);
  #pragma unroll
  for (int tap = 0; tap < 9; tap++) {
    int kh = tap / 3, kw = tap % 3;
    #pragma unroll
    for (int cg = 0; cg < 4; cg++) {
      int ci = cg * 64 + l;
      float v = wl[wave][ci * 9 + tap] * d;
      __hip_bfloat16 hb = __float2bfloat16(v);
      size_t oidx = ((((size_t)((n * 3 + kh) * 8) + (ci >> 5)) * 3 + kw) * 256 + co) * 32 + (ci & 31);
      wwg[oidx] = *reinterpret_cast<ushort_t*>(&hb);
    }
  }
}

// ---------------- K3: x NCHW f32 -> Xt NHWC bf16
__global__ void k_transpose(const float* __restrict__ x, ushort_t* __restrict__ xt) {
  int n = blockIdx.z, h = blockIdx.y;
  int wt = blockIdx.x & 1, ct = blockIdx.x >> 1;   // gridDim.x = 8
  int w0 = wt * 64, ci0 = ct * 64;
  __shared__ float tile[64][68];                   // pad 4: 16B-aligned rows
  int t = threadIdx.x;
  {
    int ci_l = t >> 2, wq = (t & 3) * 16;
    const float* src = x + (((size_t)(n * 256 + ci0 + ci_l) * 128 + h) * 128 + w0 + wq);
    #pragma unroll
    for (int j = 0; j < 4; j++)
      *(float4*)&tile[ci_l][wq + j * 4] = ((const float4*)src)[j];
  }
  __syncthreads();
  {
    int w_l = t >> 2, cq = (t & 3) * 16;
    union { ushort_t u[16]; uint4 v[2]; } pk;
    #pragma unroll
    for (int j = 0; j < 16; j++) {
      __hip_bfloat16 hb = __float2bfloat16(tile[cq + j][w_l]);
      pk.u[j] = *reinterpret_cast<ushort_t*>(&hb);
    }
    size_t off = ((size_t)((n * 128 + h) * 128) + w0 + w_l) * 256 + ci0 + cq;
    uint4* dst = (uint4*)(xt + off);
    dst[0] = pk.v[0];
    dst[1] = pk.v[1];
  }
}

// ---------------- K4: implicit-GEMM conv + bias + lrelu*sqrt2 + sigmoid
// block: (cb co-half, h-row, n); 4 waves, each 32co x 128w
// 2-phase pipeline: STAGE(next) -> compute(cur) -> syncthreads (drains loads)
// LDS dbuf: 2 x (A [kw3][co128][ci32] 24576B + B [130+][ci32] 8448B) = 66048B -> 2 blk/CU
__global__ __launch_bounds__(256, 2) void k_conv(
    const ushort_t* __restrict__ xt, const ushort_t* __restrict__ wwg,
    const float* __restrict__ bias, float* __restrict__ out) {
  __shared__ __align__(16) char smem[2 * 24576 + 2 * 8448];

  const int bid = blockIdx.x;
  const int n  = bid & 7;          // == XCD (round-robin dispatch)
  const int r  = bid >> 3;         // 0..255, increasing in time per XCD
  const int cb = r & 1;
  const int h0 = r >> 1;           // adjacent h-rows adjacent in time -> L2 reuse

  const int t = threadIdx.x;
  const int wave = t >> 6;
  const int l = t & 63;
  const int wr = wave;             // co quarter within cb half (32 co)
  const int c = l & 15, kg = l >> 4;

  f32x4 acc[2][8];
  #pragma unroll
  for (int i = 0; i < 2; i++)
    #pragma unroll
    for (int j = 0; j < 8; j++)
      acc[i][j] = (f32x4){0.f, 0.f, 0.f, 0.f};

  // zero w-border slots (slot 0 => w=-1, slot 129 => w=128) in both B buffers
  if (t < 16) {
    int buf = t >> 3, q = t & 7;
    int slot = (q >> 2) ? 129 : 0;
    *(f32x4*)(smem + 49152 + buf * 8448 + slot * 64 + (q & 3) * 16) =
        (f32x4){0.f, 0.f, 0.f, 0.f};
  }

  const long long xtN = (long long)n * (128LL * 128 * 256);
  const int khs = (h0 == 0) ? 1 : 0;
  const int khe = (h0 == 127) ? 1 : 2;   // inclusive
  const int NS = (khe - khs + 1) * 8;

  auto stage = [&](int i, int pbuf) {
    const int kh = khs + (i >> 3), cc = i & 7;
    // A: 1536 granules, 6 iters
    const char* gA = (const char*)wwg + (((size_t)(n * 3 + kh) * 8 + cc) * (3 * 256 * 32)) * 2;
    char* aDst = smem + pbuf * 24576;
    #pragma unroll
    for (int it = 0; it < 6; it++) {
      int G = it * 256 + t;
      int kw = G >> 9, rr = G & 511;
      gload16(gA + kw * 16384 + cb * 8192 + rr * 16,
              aDst + (it * 256 + wave * 64) * 16);
    }
    // B: one x-row, 512 granules, 2 iters (hsrc always in [0,127] here)
    const int hsrc = h0 + kh - 1;
    const char* gB = (const char*)xt + (xtN + (long long)hsrc * 128 * 256 + cc * 32) * 2;
    char* bDst = smem + 49152 + pbuf * 8448 + 64;
    #pragma unroll
    for (int it = 0; it < 2; it++) {
      int G = it * 256 + t;
      int w = G >> 2, gg = G & 3;
      gload16(gB + ((long long)w * 256 + gg * 8) * 2,
              bDst + (it * 256 + wave * 64) * 16);
    }
  };

  auto compute = [&](int pbuf) {
    const char* aB = smem + pbuf * 24576;
    const char* bB = smem + 49152 + pbuf * 8448;
    #pragma unroll
    for (int s = 0; s < 3; s++) {
      bf16x8 af[2];
      #pragma unroll
      for (int mi = 0; mi < 2; mi++)
        af[mi] = *(const bf16x8*)(aB + s * 8192 + (wr * 32 + mi * 16 + c) * 64 + kg * 16);
      bf16x8 bfr[8];
      #pragma unroll
      for (int ni = 0; ni < 8; ni++)
        bfr[ni] = *(const bf16x8*)(bB + (ni * 16 + c + s) * 64 + kg * 16);
      #pragma unroll
      for (int mi = 0; mi < 2; mi++)
        #pragma unroll
        for (int ni = 0; ni < 8; ni++)
          acc[mi][ni] = __builtin_amdgcn_mfma_f32_16x16x32_bf16(af[mi], bfr[ni], acc[mi][ni], 0, 0, 0);
    }
  };

  stage(0, 0);
  __syncthreads();                 // drains prologue loads + border zeroes
  for (int i = 0; i < NS; i++) {
    if (i + 1 < NS) stage(i + 1, (i + 1) & 1);   // issue next-step loads FIRST
    compute(i & 1);                               // MFMA hides load latency
    __syncthreads();                              // vmcnt(0)+barrier: next buf ready
  }

  // ---- epilogue: bias + lrelu*sqrt2 + sigmoid, write f32 NCHW
  #pragma unroll
  for (int mi = 0; mi < 2; mi++) {
    #pragma unroll
    for (int rr = 0; rr < 4; rr++) {
      int co = cb * 128 + wr * 32 + mi * 16 + kg * 4 + rr;
      float bval = bias[co];
      #pragma unroll
      for (int ni = 0; ni < 8; ni++) {
        float v = acc[mi][ni][rr] + bval;
        v = (v >= 0.f ? v : 0.2f * v) * 1.41421356237f;
        float o = 1.f / (1.f + __expf(-v));
        out[(((size_t)(n * 256 + co)) * 128 + h0) * 128 + ni * 16 + c] = o;
      }
    }
  }
}

extern "C" void kernel_launch(void* const* d_in, const int* in_sizes, int n_in,
                              void* d_out, int out_size, void* d_ws, size_t ws_size,
                              hipStream_t stream) {
  const float* x      = (const float*)d_in[0];
  const float* w      = (const float*)d_in[1];
  const float* aw     = (const float*)d_in[2];
  const float* ab     = (const float*)d_in[3];
  const float* weight = (const float*)d_in[4];
  const float* bias   = (const float*)d_in[5];
  float* out = (float*)d_out;

  char* ws = (char*)d_ws;
  float*    styles = (float*)ws;                                  // 8 KB
  ushort_t* wwg    = (ushort_t*)(ws + 8192);                      // 9,437,184 B
  ushort_t* xt     = (ushort_t*)(ws + 8192 + 9437184);            // 67,108,864 B

  k_styles<<<512, 256, 0, stream>>>(w, aw, ab, styles);
  k_modw<<<512, 256, 0, stream>>>(weight, styles, wwg);
  k_transpose<<<dim3(8, 128, 8), 256, 0, stream>>>(x, xt);
  k_conv<<<2048, 256, 0, stream>>>(xt, wwg, bias, out);
}